// Round 16
// baseline (89.459 us; speedup 1.0000x reference)
//
#include <hip/hip_runtime.h>
#include <hip/hip_fp16.h>
#include <math.h>

#define N_NODES 50000
#define N_EDGES 800000
#define D_IN    64
#define H_HID   16
#define C_OUT   40

#define BSH     7                                  // 128 nodes per bucket
#define BNODES  128
#define BMASK   127
#define NBUCK   ((N_NODES + BNODES - 1) / BNODES)  // 391
#define NBUCKP  400                                // padded stride for part arrays
#define NBLK    1000                               // edge slabs
#define EPB     (N_EDGES / NBLK)                   // 800 exact, 16B-aligned
#define EPB4    (EPB / 4)                          // 200 int4s per slab

// ---- pass A: per-(block,bucket) histograms, LDS only; part[block][bucket] ----
__global__ void bucket_count(const int* __restrict__ src, const int* __restrict__ dst,
                             int* __restrict__ partS, int* __restrict__ partD) {
    __shared__ int hS[NBUCK], hD[NBUCK];
    for (int i = threadIdx.x; i < NBUCK; i += blockDim.x) { hS[i] = 0; hD[i] = 0; }
    __syncthreads();
    const int4* s4 = (const int4*)(src + blockIdx.x * EPB);
    const int4* d4 = (const int4*)(dst + blockIdx.x * EPB);
    for (int k = threadIdx.x; k < EPB4; k += blockDim.x) {
        int4 s = s4[k], d = d4[k];
        atomicAdd(&hS[s.x >> BSH], 1); atomicAdd(&hS[s.y >> BSH], 1);
        atomicAdd(&hS[s.z >> BSH], 1); atomicAdd(&hS[s.w >> BSH], 1);
        atomicAdd(&hD[d.x >> BSH], 1); atomicAdd(&hD[d.y >> BSH], 1);
        atomicAdd(&hD[d.z >> BSH], 1); atomicAdd(&hD[d.w >> BSH], 1);
    }
    __syncthreads();
    for (int i = threadIdx.x; i < NBUCK; i += blockDim.x) {
        partS[blockIdx.x * NBUCKP + i] = hS[i];
        partD[blockIdx.x * NBUCKP + i] = hD[i];
    }
}

// ---- prefix over blocks, one block per (bucket, S/D): part[k][b] <- sum_{k'<k} ----
__global__ void bucket_base_scan(int* __restrict__ partS, int* __restrict__ partD,
                                 int* __restrict__ totS, int* __restrict__ totD) {
    int* part = blockIdx.y ? partD : partS;
    int* tot  = blockIdx.y ? totD  : totS;
    int b = blockIdx.x;
    __shared__ int s[1024];
    int k = threadIdx.x;
    int v = (k < NBLK) ? part[k * NBUCKP + b] : 0;
    s[k] = v;
    __syncthreads();
    for (int off = 1; off < 1024; off <<= 1) {
        int t = (k >= off) ? s[k - off] : 0;
        __syncthreads();
        s[k] += t;
        __syncthreads();
    }
    if (k < NBLK) part[k * NBUCKP + b] = s[k] - v;   // exclusive within bucket
    if (k == 1023) tot[b] = s[1023];
}

// ---- exclusive scan of bucket totals -> base ----
__global__ void bucket_base_final(const int* __restrict__ totS, const int* __restrict__ totD,
                                  int* __restrict__ baseS, int* __restrict__ baseD) {
    const int* tot = blockIdx.x ? totD : totS;
    int* base = blockIdx.x ? baseD : baseS;
    __shared__ int s[512];
    int k = threadIdx.x;
    int v = (k < NBUCK) ? tot[k] : 0;
    s[k] = v;
    __syncthreads();
    for (int off = 1; off < 512; off <<= 1) {
        int t = (k >= off) ? s[k - off] : 0;
        __syncthreads();
        s[k] += t;
        __syncthreads();
    }
    if (k < NBUCK) base[k] = s[k] - v;
    if (k == NBUCK - 1) base[NBUCK] = s[k];   // total == N_EDGES
}

// ---- pass B: scatter edges into bucket-grouped arrays; cursors = 2 coalesced loads ----
__global__ void bucket_scatter(const int* __restrict__ src, const int* __restrict__ dst,
                               const int* __restrict__ partS, const int* __restrict__ partD,
                               const int* __restrict__ baseS, const int* __restrict__ baseD,
                               unsigned int* __restrict__ packedD,
                               unsigned char* __restrict__ srcloc) {
    __shared__ int cS[NBUCK], cD[NBUCK];
    int blk = blockIdx.x;
    for (int b = threadIdx.x; b < NBUCK; b += blockDim.x) {
        cS[b] = baseS[b] + partS[blk * NBUCKP + b];
        cD[b] = baseD[b] + partD[blk * NBUCKP + b];
    }
    __syncthreads();
    const int4* s4 = (const int4*)(src + blk * EPB);
    const int4* d4 = (const int4*)(dst + blk * EPB);
    for (int k = threadIdx.x; k < EPB4; k += blockDim.x) {
        int4 sv = s4[k], dv = d4[k];
        int ss[4] = { sv.x, sv.y, sv.z, sv.w };
        int dd[4] = { dv.x, dv.y, dv.z, dv.w };
        #pragma unroll
        for (int u = 0; u < 4; ++u) {
            int s = ss[u], d = dd[u];
            int pD = atomicAdd(&cD[d >> BSH], 1);
            packedD[pD] = (unsigned)s | ((unsigned)(d & BMASK) << 16);
            int pS = atomicAdd(&cS[s >> BSH], 1);
            srcloc[pS] = (unsigned char)(s & BMASK);
        }
    }
}

// ---- per-bucket counting sort -> per-node CSR (ushort col, rowptr) + dinv ----
__global__ void csr_build(const unsigned int* __restrict__ packedD, const int* __restrict__ baseD,
                          const unsigned char* __restrict__ srcloc, const int* __restrict__ baseS,
                          unsigned short* __restrict__ col, int* __restrict__ rowptr,
                          float* __restrict__ dinv) {
    __shared__ int hist[BNODES], scanv[BNODES], cur[BNODES], shist[BNODES];
    int tid = threadIdx.x;
    if (tid < BNODES) { hist[tid] = 0; shist[tid] = 0; }
    __syncthreads();
    int bb = blockIdx.x;
    int begD = baseD[bb], endD = baseD[bb + 1];
    for (int j = begD + tid; j < endD; j += blockDim.x)
        atomicAdd(&hist[(packedD[j] >> 16) & BMASK], 1);
    int begS = baseS[bb], endS = baseS[bb + 1];
    for (int j = begS + tid; j < endS; j += blockDim.x)
        atomicAdd(&shist[srcloc[j]], 1);
    __syncthreads();
    if (tid == 0) {
        int acc = 0;
        for (int i = 0; i < BNODES; ++i) { scanv[i] = acc; acc += hist[i]; }
    }
    __syncthreads();
    if (tid < BNODES) {
        cur[tid] = scanv[tid];
        int node = bb * BNODES + tid;
        if (node < N_NODES) {
            rowptr[node] = begD + scanv[tid];
            int d = shist[tid];
            dinv[node] = (d > 0) ? rsqrtf((float)d) : 0.0f;
        }
    }
    if (bb == NBUCK - 1 && tid == 0) rowptr[N_NODES] = endD;   // == N_EDGES
    __syncthreads();
    for (int j = begD + tid; j < endD; j += blockDim.x) {
        unsigned rec = packedD[j];
        int dl = (rec >> 16) & BMASK;
        int pos = atomicAdd(&cur[dl], 1);
        col[begD + pos] = (unsigned short)(rec & 0xFFFF);   // src id fits 16b (N<65536)
    }
}

// ---- xw0 = x@W1[0] (fp32); sxw1 = dinv * (x@W1[1]) stored as fp16 ----
__global__ void xw_kernel(const float* __restrict__ x, const float* __restrict__ W1,
                          const float* __restrict__ dinv,
                          float* __restrict__ xw0, __half* __restrict__ sxw1h) {
    __shared__ float sW[2 * D_IN * H_HID];   // 8 KB
    __shared__ float sx[16 * 65];
    for (int i = threadIdx.x; i < 2 * D_IN * H_HID; i += 256) sW[i] = W1[i];
    int nbase = blockIdx.x * 16;
    for (int i = threadIdx.x; i < 16 * D_IN; i += 256) {
        int r = i >> 6, c = i & 63;
        sx[r * 65 + c] = x[(size_t)(nbase + r) * D_IN + c];
    }
    __syncthreads();
    int nl = threadIdx.x >> 4, f = threadIdx.x & 15;
    int node = nbase + nl;                    // N = 3125*16 exactly
    float a0 = 0.f, a1 = 0.f;
    #pragma unroll
    for (int d = 0; d < D_IN; ++d) {
        float xv = sx[nl * 65 + d];
        a0 += xv * sW[d * H_HID + f];
        a1 += xv * sW[D_IN * H_HID + d * H_HID + f];
    }
    int t = node * H_HID + f;
    xw0[t]   = a0;
    sxw1h[t] = __float2half_rn(dinv[node] * a1);
}

// unpack uint2 (4 halves) and accumulate into 4 fp32 accumulators
#define ACC4(V)                                                       \
    {                                                                 \
        __half2 p0 = *reinterpret_cast<const __half2*>(&(V).x);       \
        __half2 p1 = *reinterpret_cast<const __half2*>(&(V).y);       \
        float2 f0 = __half22float2(p0), f1 = __half22float2(p1);      \
        a0 += f0.x; a1 += f0.y; a2 += f1.x; a3 += f1.y;               \
    }

// 16/8/1-deep gather over fp16 table (uint2 = 4 halves per lane)
#define GATHERH(TBL)                                                  \
    for (; j + 16 <= end; j += 16) {                                  \
        int cc[16];                                                   \
        _Pragma("unroll")                                             \
        for (int u = 0; u < 16; ++u) cc[u] = col[j + u];              \
        uint2 vv[16];                                                 \
        _Pragma("unroll")                                             \
        for (int u = 0; u < 16; ++u) vv[u] = TBL[cc[u] * 4 + f4];     \
        _Pragma("unroll")                                             \
        for (int u = 0; u < 16; ++u) ACC4(vv[u])                      \
    }                                                                 \
    for (; j + 8 <= end; j += 8) {                                    \
        int cc[8];                                                    \
        _Pragma("unroll")                                             \
        for (int u = 0; u < 8; ++u) cc[u] = col[j + u];               \
        uint2 vv[8];                                                  \
        _Pragma("unroll")                                             \
        for (int u = 0; u < 8; ++u) vv[u] = TBL[cc[u] * 4 + f4];      \
        _Pragma("unroll")                                             \
        for (int u = 0; u < 8; ++u) ACC4(vv[u])                       \
    }                                                                 \
    for (; j < end; ++j) {                                            \
        uint2 v = TBL[col[j] * 4 + f4];                               \
        ACC4(v)                                                       \
    }

// ---- layer-1 gather: 4 lanes/node, fp16 table, 64 nodes per 256-thread block ----
__global__ void gather1(const int* __restrict__ rowptr, const unsigned short* __restrict__ col,
                        const float* __restrict__ dinv, const uint2* __restrict__ sxw1h,
                        const float* __restrict__ xw0, const float* __restrict__ b1,
                        uint2* __restrict__ h16, uint2* __restrict__ sh16) {
    int grp = threadIdx.x >> 2;               // 64 groups per 256-thread block
    int f4  = threadIdx.x & 3;
    int node = blockIdx.x * 64 + grp;
    if (node >= N_NODES) return;
    int beg = rowptr[node], end = rowptr[node + 1];
    float a0 = 0.f, a1 = 0.f, a2 = 0.f, a3 = 0.f;
    int j = beg;
    GATHERH(sxw1h)
    float di = dinv[node];
    float4 x0 = ((const float4*)xw0)[node * 4 + f4];
    float4 bb = ((const float4*)b1)[f4];
    float v0 = fmaxf(x0.x - di * a0 + bb.x, 0.f);
    float v1 = fmaxf(x0.y - di * a1 + bb.y, 0.f);
    float v2 = fmaxf(x0.z - di * a2 + bb.z, 0.f);
    float v3 = fmaxf(x0.w - di * a3 + bb.w, 0.f);
    uint2 hw, sw;
    *reinterpret_cast<__half2*>(&hw.x) = __float22half2_rn(make_float2(v0, v1));
    *reinterpret_cast<__half2*>(&hw.y) = __float22half2_rn(make_float2(v2, v3));
    *reinterpret_cast<__half2*>(&sw.x) = __float22half2_rn(make_float2(di * v0, di * v1));
    *reinterpret_cast<__half2*>(&sw.y) = __float22half2_rn(make_float2(di * v2, di * v3));
    h16[node * 4 + f4]  = hw;
    sh16[node * 4 + f4] = sw;
}

// ---- layer-2 gather FUSED with dual matmul + log_softmax ----
#define HROW 20   // padded LDS row stride
__global__ void gather2_out(const int* __restrict__ rowptr, const unsigned short* __restrict__ col,
                            const float* __restrict__ dinv, const uint2* __restrict__ sh16,
                            const uint2* __restrict__ h16, const float* __restrict__ W2,
                            const float* __restrict__ b2, float* __restrict__ out) {
    __shared__ float sW0[H_HID * C_OUT], sW1[H_HID * C_OUT], sb[C_OUT];
    __shared__ float hrow[64][HROW];    // 5 KB
    __shared__ float trow[64][HROW];    // 5 KB
    for (int i = threadIdx.x; i < H_HID * C_OUT; i += 256) {
        sW0[i] = W2[i];
        sW1[i] = W2[H_HID * C_OUT + i];
    }
    if (threadIdx.x < C_OUT) sb[threadIdx.x] = b2[threadIdx.x];

    int grp = threadIdx.x >> 2;
    int f4  = threadIdx.x & 3;
    int node = blockIdx.x * 64 + grp;
    bool active = node < N_NODES;
    int beg = 0, end = 0;
    float di = 0.f;
    if (active) { beg = rowptr[node]; end = rowptr[node + 1]; di = dinv[node]; }
    float a0 = 0.f, a1 = 0.f, a2 = 0.f, a3 = 0.f;
    int j = beg;
    GATHERH(sh16)
    // stage h row (unpacked) and t1 row into LDS
    float h0 = 0.f, h1 = 0.f, h2 = 0.f, h3 = 0.f;
    if (active) {
        uint2 hv2 = h16[node * 4 + f4];
        __half2 p0 = *reinterpret_cast<const __half2*>(&hv2.x);
        __half2 p1 = *reinterpret_cast<const __half2*>(&hv2.y);
        float2 f0 = __half22float2(p0), f1 = __half22float2(p1);
        h0 = f0.x; h1 = f0.y; h2 = f1.x; h3 = f1.y;
    }
    hrow[grp][4 * f4 + 0] = h0;
    hrow[grp][4 * f4 + 1] = h1;
    hrow[grp][4 * f4 + 2] = h2;
    hrow[grp][4 * f4 + 3] = h3;
    trow[grp][4 * f4 + 0] = -di * a0;
    trow[grp][4 * f4 + 1] = -di * a1;
    trow[grp][4 * f4 + 2] = -di * a2;
    trow[grp][4 * f4 + 3] = -di * a3;
    __syncthreads();

    float hv[H_HID], tv[H_HID];
    #pragma unroll
    for (int ff = 0; ff < H_HID; ++ff) {
        hv[ff] = hrow[grp][ff];
        tv[ff] = trow[grp][ff];
    }
    float o[10];
    float mx = -1e30f;
    #pragma unroll
    for (int i = 0; i < 10; ++i) {
        int c = f4 * 10 + i;
        float aa = sb[c];
        #pragma unroll
        for (int ff = 0; ff < H_HID; ++ff)
            aa += hv[ff] * sW0[ff * C_OUT + c] + tv[ff] * sW1[ff * C_OUT + c];
        o[i] = aa;
        mx = fmaxf(mx, aa);
    }
    mx = fmaxf(mx, __shfl_xor(mx, 1));
    mx = fmaxf(mx, __shfl_xor(mx, 2));
    float sum = 0.f;
    #pragma unroll
    for (int i = 0; i < 10; ++i) sum += expf(o[i] - mx);
    sum += __shfl_xor(sum, 1);
    sum += __shfl_xor(sum, 2);
    float lse = mx + logf(sum);
    if (active) {
        float* op = out + (size_t)node * C_OUT + f4 * 10;
        #pragma unroll
        for (int i = 0; i < 10; ++i) op[i] = o[i] - lse;
    }
}

extern "C" void kernel_launch(void* const* d_in, const int* in_sizes, int n_in,
                              void* d_out, int out_size, void* d_ws, size_t ws_size,
                              hipStream_t stream) {
    const float* x   = (const float*)d_in[0];
    const int*   ei  = (const int*)d_in[1];
    const float* W1  = (const float*)d_in[2];
    const float* b1  = (const float*)d_in[3];
    const float* W2  = (const float*)d_in[4];
    const float* b2  = (const float*)d_in[5];
    float* out = (float*)d_out;

    const int* src = ei;            // edge_index[0]
    const int* dst = ei + N_EDGES;  // edge_index[1]

    // workspace layout
    int* partS = (int*)d_ws;                                      // NBLK*NBUCKP
    int* partD = partS + NBLK * NBUCKP;                           // NBLK*NBUCKP
    int* baseS = partD + NBLK * NBUCKP;                           // NBUCK+1 (pad 512)
    int* baseD = baseS + 512;                                     // NBUCK+1 (pad 512)
    int* totS  = baseD + 512;                                     // NBUCK (pad 512)
    int* totD  = totS + 512;                                      // NBUCK (pad 512)
    unsigned int*   packedD = (unsigned int*)(totD + 512);        // E
    unsigned char*  srcloc  = (unsigned char*)(packedD + N_EDGES);// E bytes
    unsigned short* col     = (unsigned short*)(srcloc + N_EDGES);// E ushorts (E even)
    int*   rowptr = (int*)(col + N_EDGES);                        // N+1 (pad 8)
    float* dinv   = (float*)(rowptr + N_NODES + 8);               // N
    float* xw0    = dinv + N_NODES;                               // N*16 fp32
    __half* sxw1h = (__half*)(xw0 + (size_t)N_NODES * H_HID);     // N*16 fp16
    __half* h16   = sxw1h + (size_t)N_NODES * H_HID;              // N*16 fp16
    __half* sh16  = h16   + (size_t)N_NODES * H_HID;              // N*16 fp16

    bucket_count     <<<NBLK, 256, 0, stream>>>(src, dst, partS, partD);
    bucket_base_scan <<<dim3(NBUCK, 2), 1024, 0, stream>>>(partS, partD, totS, totD);
    bucket_base_final<<<2, 512, 0, stream>>>(totS, totD, baseS, baseD);
    bucket_scatter   <<<NBLK, 256, 0, stream>>>(src, dst, partS, partD, baseS, baseD, packedD, srcloc);
    csr_build        <<<NBUCK, 1024, 0, stream>>>(packedD, baseD, srcloc, baseS, col, rowptr, dinv);
    xw_kernel        <<<N_NODES / 16, 256, 0, stream>>>(x, W1, dinv, xw0, sxw1h);
    gather1          <<<(N_NODES + 63) / 64, 256, 0, stream>>>(rowptr, col, dinv, (const uint2*)sxw1h,
                                                               xw0, b1, (uint2*)h16, (uint2*)sh16);
    gather2_out      <<<(N_NODES + 63) / 64, 256, 0, stream>>>(rowptr, col, dinv, (const uint2*)sh16,
                                                               (const uint2*)h16, W2, b2, out);
}

// Round 17
// 82.110 us; speedup vs baseline: 1.0895x; 1.0895x over previous
//
#include <hip/hip_runtime.h>
#include <hip/hip_fp16.h>
#include <math.h>

#define N_NODES 50000
#define N_EDGES 800000
#define D_IN    64
#define H_HID   16
#define C_OUT   40

#define BSH     7                                  // 128 nodes per bucket
#define BNODES  128
#define BMASK   127
#define NBUCK   ((N_NODES + BNODES - 1) / BNODES)  // 391
#define NBUCKP  400                                // padded stride for part arrays
#define NBLK    500                                // edge slabs
#define EPB     (N_EDGES / NBLK)                   // 1600 exact, 16B-aligned
#define EPB4    (EPB / 4)                          // 400 int4s per slab

// ---- pass A: per-(block,bucket) histograms, LDS only; part[block][bucket] ----
__global__ void bucket_count(const int* __restrict__ src, const int* __restrict__ dst,
                             int* __restrict__ partS, int* __restrict__ partD) {
    __shared__ int hS[NBUCK], hD[NBUCK];
    for (int i = threadIdx.x; i < NBUCK; i += blockDim.x) { hS[i] = 0; hD[i] = 0; }
    __syncthreads();
    const int4* s4 = (const int4*)(src + blockIdx.x * EPB);
    const int4* d4 = (const int4*)(dst + blockIdx.x * EPB);
    for (int k = threadIdx.x; k < EPB4; k += blockDim.x) {
        int4 s = s4[k], d = d4[k];
        atomicAdd(&hS[s.x >> BSH], 1); atomicAdd(&hS[s.y >> BSH], 1);
        atomicAdd(&hS[s.z >> BSH], 1); atomicAdd(&hS[s.w >> BSH], 1);
        atomicAdd(&hD[d.x >> BSH], 1); atomicAdd(&hD[d.y >> BSH], 1);
        atomicAdd(&hD[d.z >> BSH], 1); atomicAdd(&hD[d.w >> BSH], 1);
    }
    __syncthreads();
    for (int i = threadIdx.x; i < NBUCK; i += blockDim.x) {
        partS[blockIdx.x * NBUCKP + i] = hS[i];
        partD[blockIdx.x * NBUCKP + i] = hD[i];
    }
}

// ---- prefix over blocks, one block per (bucket, S/D): part[k][b] <- sum_{k'<k} ----
__global__ void bucket_base_scan(int* __restrict__ partS, int* __restrict__ partD,
                                 int* __restrict__ totS, int* __restrict__ totD) {
    int* part = blockIdx.y ? partD : partS;
    int* tot  = blockIdx.y ? totD  : totS;
    int b = blockIdx.x;
    __shared__ int s[512];
    int k = threadIdx.x;
    int v = (k < NBLK) ? part[k * NBUCKP + b] : 0;
    s[k] = v;
    __syncthreads();
    for (int off = 1; off < 512; off <<= 1) {
        int t = (k >= off) ? s[k - off] : 0;
        __syncthreads();
        s[k] += t;
        __syncthreads();
    }
    if (k < NBLK) part[k * NBUCKP + b] = s[k] - v;   // exclusive within bucket
    if (k == 511) tot[b] = s[511];
}

// ---- exclusive scan of bucket totals -> base ----
__global__ void bucket_base_final(const int* __restrict__ totS, const int* __restrict__ totD,
                                  int* __restrict__ baseS, int* __restrict__ baseD) {
    const int* tot = blockIdx.x ? totD : totS;
    int* base = blockIdx.x ? baseD : baseS;
    __shared__ int s[512];
    int k = threadIdx.x;
    int v = (k < NBUCK) ? tot[k] : 0;
    s[k] = v;
    __syncthreads();
    for (int off = 1; off < 512; off <<= 1) {
        int t = (k >= off) ? s[k - off] : 0;
        __syncthreads();
        s[k] += t;
        __syncthreads();
    }
    if (k < NBUCK) base[k] = s[k] - v;
    if (k == NBUCK - 1) base[NBUCK] = s[k];   // total == N_EDGES
}

// ---- pass B: scatter edges into bucket-grouped arrays; cursors = 2 coalesced loads ----
__global__ void bucket_scatter(const int* __restrict__ src, const int* __restrict__ dst,
                               const int* __restrict__ partS, const int* __restrict__ partD,
                               const int* __restrict__ baseS, const int* __restrict__ baseD,
                               unsigned int* __restrict__ packedD,
                               unsigned char* __restrict__ srcloc) {
    __shared__ int cS[NBUCK], cD[NBUCK];
    int blk = blockIdx.x;
    for (int b = threadIdx.x; b < NBUCK; b += blockDim.x) {
        cS[b] = baseS[b] + partS[blk * NBUCKP + b];
        cD[b] = baseD[b] + partD[blk * NBUCKP + b];
    }
    __syncthreads();
    const int4* s4 = (const int4*)(src + blk * EPB);
    const int4* d4 = (const int4*)(dst + blk * EPB);
    for (int k = threadIdx.x; k < EPB4; k += blockDim.x) {
        int4 sv = s4[k], dv = d4[k];
        int ss[4] = { sv.x, sv.y, sv.z, sv.w };
        int dd[4] = { dv.x, dv.y, dv.z, dv.w };
        #pragma unroll
        for (int u = 0; u < 4; ++u) {
            int s = ss[u], d = dd[u];
            int pD = atomicAdd(&cD[d >> BSH], 1);
            packedD[pD] = (unsigned)s | ((unsigned)(d & BMASK) << 16);
            int pS = atomicAdd(&cS[s >> BSH], 1);
            srcloc[pS] = (unsigned char)(s & BMASK);
        }
    }
}

// ---- per-bucket counting sort -> per-node CSR (ushort col, rowptr) + dinv ----
__global__ void csr_build(const unsigned int* __restrict__ packedD, const int* __restrict__ baseD,
                          const unsigned char* __restrict__ srcloc, const int* __restrict__ baseS,
                          unsigned short* __restrict__ col, int* __restrict__ rowptr,
                          float* __restrict__ dinv) {
    __shared__ int hist[BNODES], scanv[BNODES], cur[BNODES], shist[BNODES];
    int tid = threadIdx.x;
    if (tid < BNODES) { hist[tid] = 0; shist[tid] = 0; }
    __syncthreads();
    int bb = blockIdx.x;
    int begD = baseD[bb], endD = baseD[bb + 1];
    for (int j = begD + tid; j < endD; j += blockDim.x)
        atomicAdd(&hist[(packedD[j] >> 16) & BMASK], 1);
    int begS = baseS[bb], endS = baseS[bb + 1];
    for (int j = begS + tid; j < endS; j += blockDim.x)
        atomicAdd(&shist[srcloc[j]], 1);
    __syncthreads();
    if (tid == 0) {
        int acc = 0;
        for (int i = 0; i < BNODES; ++i) { scanv[i] = acc; acc += hist[i]; }
    }
    __syncthreads();
    if (tid < BNODES) {
        cur[tid] = scanv[tid];
        int node = bb * BNODES + tid;
        if (node < N_NODES) {
            rowptr[node] = begD + scanv[tid];
            int d = shist[tid];
            dinv[node] = (d > 0) ? rsqrtf((float)d) : 0.0f;
        }
    }
    if (bb == NBUCK - 1 && tid == 0) rowptr[N_NODES] = endD;   // == N_EDGES
    __syncthreads();
    for (int j = begD + tid; j < endD; j += blockDim.x) {
        unsigned rec = packedD[j];
        int dl = (rec >> 16) & BMASK;
        int pos = atomicAdd(&cur[dl], 1);
        col[begD + pos] = (unsigned short)(rec & 0xFFFF);   // src id fits 16b (N<65536)
    }
}

// ---- xw0 = x@W1[0] (fp32); sxw1 = dinv * (x@W1[1]) stored as fp16 ----
__global__ void xw_kernel(const float* __restrict__ x, const float* __restrict__ W1,
                          const float* __restrict__ dinv,
                          float* __restrict__ xw0, __half* __restrict__ sxw1h) {
    __shared__ float sW[2 * D_IN * H_HID];   // 8 KB
    __shared__ float sx[16 * 65];
    for (int i = threadIdx.x; i < 2 * D_IN * H_HID; i += 256) sW[i] = W1[i];
    int nbase = blockIdx.x * 16;
    for (int i = threadIdx.x; i < 16 * D_IN; i += 256) {
        int r = i >> 6, c = i & 63;
        sx[r * 65 + c] = x[(size_t)(nbase + r) * D_IN + c];
    }
    __syncthreads();
    int nl = threadIdx.x >> 4, f = threadIdx.x & 15;
    int node = nbase + nl;                    // N = 3125*16 exactly
    float a0 = 0.f, a1 = 0.f;
    #pragma unroll
    for (int d = 0; d < D_IN; ++d) {
        float xv = sx[nl * 65 + d];
        a0 += xv * sW[d * H_HID + f];
        a1 += xv * sW[D_IN * H_HID + d * H_HID + f];
    }
    int t = node * H_HID + f;
    xw0[t]   = a0;
    sxw1h[t] = __float2half_rn(dinv[node] * a1);
}

// unpack uint2 (4 halves) and accumulate into 4 fp32 accumulators
#define ACC4(V)                                                       \
    {                                                                 \
        __half2 p0 = *reinterpret_cast<const __half2*>(&(V).x);       \
        __half2 p1 = *reinterpret_cast<const __half2*>(&(V).y);       \
        float2 f0 = __half22float2(p0), f1 = __half22float2(p1);      \
        a0 += f0.x; a1 += f0.y; a2 += f1.x; a3 += f1.y;               \
    }

// 16/8/1-deep gather over fp16 table (uint2 = 4 halves per lane)
#define GATHERH(TBL)                                                  \
    for (; j + 16 <= end; j += 16) {                                  \
        int cc[16];                                                   \
        _Pragma("unroll")                                             \
        for (int u = 0; u < 16; ++u) cc[u] = col[j + u];              \
        uint2 vv[16];                                                 \
        _Pragma("unroll")                                             \
        for (int u = 0; u < 16; ++u) vv[u] = TBL[cc[u] * 4 + f4];     \
        _Pragma("unroll")                                             \
        for (int u = 0; u < 16; ++u) ACC4(vv[u])                      \
    }                                                                 \
    for (; j + 8 <= end; j += 8) {                                    \
        int cc[8];                                                    \
        _Pragma("unroll")                                             \
        for (int u = 0; u < 8; ++u) cc[u] = col[j + u];               \
        uint2 vv[8];                                                  \
        _Pragma("unroll")                                             \
        for (int u = 0; u < 8; ++u) vv[u] = TBL[cc[u] * 4 + f4];      \
        _Pragma("unroll")                                             \
        for (int u = 0; u < 8; ++u) ACC4(vv[u])                       \
    }                                                                 \
    for (; j < end; ++j) {                                            \
        uint2 v = TBL[col[j] * 4 + f4];                               \
        ACC4(v)                                                       \
    }

// ---- layer-1 gather: 4 lanes/node, fp16 table, 64 nodes per 256-thread block ----
__global__ void gather1(const int* __restrict__ rowptr, const unsigned short* __restrict__ col,
                        const float* __restrict__ dinv, const uint2* __restrict__ sxw1h,
                        const float* __restrict__ xw0, const float* __restrict__ b1,
                        uint2* __restrict__ h16, uint2* __restrict__ sh16) {
    int grp = threadIdx.x >> 2;               // 64 groups per 256-thread block
    int f4  = threadIdx.x & 3;
    int node = blockIdx.x * 64 + grp;
    if (node >= N_NODES) return;
    int beg = rowptr[node], end = rowptr[node + 1];
    float a0 = 0.f, a1 = 0.f, a2 = 0.f, a3 = 0.f;
    int j = beg;
    GATHERH(sxw1h)
    float di = dinv[node];
    float4 x0 = ((const float4*)xw0)[node * 4 + f4];
    float4 bb = ((const float4*)b1)[f4];
    float v0 = fmaxf(x0.x - di * a0 + bb.x, 0.f);
    float v1 = fmaxf(x0.y - di * a1 + bb.y, 0.f);
    float v2 = fmaxf(x0.z - di * a2 + bb.z, 0.f);
    float v3 = fmaxf(x0.w - di * a3 + bb.w, 0.f);
    uint2 hw, sw;
    *reinterpret_cast<__half2*>(&hw.x) = __float22half2_rn(make_float2(v0, v1));
    *reinterpret_cast<__half2*>(&hw.y) = __float22half2_rn(make_float2(v2, v3));
    *reinterpret_cast<__half2*>(&sw.x) = __float22half2_rn(make_float2(di * v0, di * v1));
    *reinterpret_cast<__half2*>(&sw.y) = __float22half2_rn(make_float2(di * v2, di * v3));
    h16[node * 4 + f4]  = hw;
    sh16[node * 4 + f4] = sw;
}

// ---- layer-2 gather FUSED with dual matmul + log_softmax ----
#define HROW 20   // padded LDS row stride
__global__ void gather2_out(const int* __restrict__ rowptr, const unsigned short* __restrict__ col,
                            const float* __restrict__ dinv, const uint2* __restrict__ sh16,
                            const uint2* __restrict__ h16, const float* __restrict__ W2,
                            const float* __restrict__ b2, float* __restrict__ out) {
    __shared__ float sW0[H_HID * C_OUT], sW1[H_HID * C_OUT], sb[C_OUT];
    __shared__ float hrow[64][HROW];    // 5 KB
    __shared__ float trow[64][HROW];    // 5 KB
    for (int i = threadIdx.x; i < H_HID * C_OUT; i += 256) {
        sW0[i] = W2[i];
        sW1[i] = W2[H_HID * C_OUT + i];
    }
    if (threadIdx.x < C_OUT) sb[threadIdx.x] = b2[threadIdx.x];

    int grp = threadIdx.x >> 2;
    int f4  = threadIdx.x & 3;
    int node = blockIdx.x * 64 + grp;
    bool active = node < N_NODES;
    int beg = 0, end = 0;
    float di = 0.f;
    if (active) { beg = rowptr[node]; end = rowptr[node + 1]; di = dinv[node]; }
    float a0 = 0.f, a1 = 0.f, a2 = 0.f, a3 = 0.f;
    int j = beg;
    GATHERH(sh16)
    // stage h row (unpacked) and t1 row into LDS
    float h0 = 0.f, h1 = 0.f, h2 = 0.f, h3 = 0.f;
    if (active) {
        uint2 hv2 = h16[node * 4 + f4];
        __half2 p0 = *reinterpret_cast<const __half2*>(&hv2.x);
        __half2 p1 = *reinterpret_cast<const __half2*>(&hv2.y);
        float2 f0 = __half22float2(p0), f1 = __half22float2(p1);
        h0 = f0.x; h1 = f0.y; h2 = f1.x; h3 = f1.y;
    }
    hrow[grp][4 * f4 + 0] = h0;
    hrow[grp][4 * f4 + 1] = h1;
    hrow[grp][4 * f4 + 2] = h2;
    hrow[grp][4 * f4 + 3] = h3;
    trow[grp][4 * f4 + 0] = -di * a0;
    trow[grp][4 * f4 + 1] = -di * a1;
    trow[grp][4 * f4 + 2] = -di * a2;
    trow[grp][4 * f4 + 3] = -di * a3;
    __syncthreads();

    float hv[H_HID], tv[H_HID];
    #pragma unroll
    for (int ff = 0; ff < H_HID; ++ff) {
        hv[ff] = hrow[grp][ff];
        tv[ff] = trow[grp][ff];
    }
    float o[10];
    float mx = -1e30f;
    #pragma unroll
    for (int i = 0; i < 10; ++i) {
        int c = f4 * 10 + i;
        float aa = sb[c];
        #pragma unroll
        for (int ff = 0; ff < H_HID; ++ff)
            aa += hv[ff] * sW0[ff * C_OUT + c] + tv[ff] * sW1[ff * C_OUT + c];
        o[i] = aa;
        mx = fmaxf(mx, aa);
    }
    mx = fmaxf(mx, __shfl_xor(mx, 1));
    mx = fmaxf(mx, __shfl_xor(mx, 2));
    float sum = 0.f;
    #pragma unroll
    for (int i = 0; i < 10; ++i) sum += expf(o[i] - mx);
    sum += __shfl_xor(sum, 1);
    sum += __shfl_xor(sum, 2);
    float lse = mx + logf(sum);
    if (active) {
        float* op = out + (size_t)node * C_OUT + f4 * 10;
        #pragma unroll
        for (int i = 0; i < 10; ++i) op[i] = o[i] - lse;
    }
}

extern "C" void kernel_launch(void* const* d_in, const int* in_sizes, int n_in,
                              void* d_out, int out_size, void* d_ws, size_t ws_size,
                              hipStream_t stream) {
    const float* x   = (const float*)d_in[0];
    const int*   ei  = (const int*)d_in[1];
    const float* W1  = (const float*)d_in[2];
    const float* b1  = (const float*)d_in[3];
    const float* W2  = (const float*)d_in[4];
    const float* b2  = (const float*)d_in[5];
    float* out = (float*)d_out;

    const int* src = ei;            // edge_index[0]
    const int* dst = ei + N_EDGES;  // edge_index[1]

    // workspace layout
    int* partS = (int*)d_ws;                                      // NBLK*NBUCKP
    int* partD = partS + NBLK * NBUCKP;                           // NBLK*NBUCKP
    int* baseS = partD + NBLK * NBUCKP;                           // NBUCK+1 (pad 512)
    int* baseD = baseS + 512;                                     // NBUCK+1 (pad 512)
    int* totS  = baseD + 512;                                     // NBUCK (pad 512)
    int* totD  = totS + 512;                                      // NBUCK (pad 512)
    unsigned int*   packedD = (unsigned int*)(totD + 512);        // E
    unsigned char*  srcloc  = (unsigned char*)(packedD + N_EDGES);// E bytes
    unsigned short* col     = (unsigned short*)(srcloc + N_EDGES);// E ushorts (E even)
    int*   rowptr = (int*)(col + N_EDGES);                        // N+1 (pad 8)
    float* dinv   = (float*)(rowptr + N_NODES + 8);               // N
    float* xw0    = dinv + N_NODES;                               // N*16 fp32
    __half* sxw1h = (__half*)(xw0 + (size_t)N_NODES * H_HID);     // N*16 fp16
    __half* h16   = sxw1h + (size_t)N_NODES * H_HID;              // N*16 fp16
    __half* sh16  = h16   + (size_t)N_NODES * H_HID;              // N*16 fp16

    bucket_count     <<<NBLK, 256, 0, stream>>>(src, dst, partS, partD);
    bucket_base_scan <<<dim3(NBUCK, 2), 512, 0, stream>>>(partS, partD, totS, totD);
    bucket_base_final<<<2, 512, 0, stream>>>(totS, totD, baseS, baseD);
    bucket_scatter   <<<NBLK, 256, 0, stream>>>(src, dst, partS, partD, baseS, baseD, packedD, srcloc);
    csr_build        <<<NBUCK, 512, 0, stream>>>(packedD, baseD, srcloc, baseS, col, rowptr, dinv);
    xw_kernel        <<<N_NODES / 16, 256, 0, stream>>>(x, W1, dinv, xw0, sxw1h);
    gather1          <<<(N_NODES + 63) / 64, 256, 0, stream>>>(rowptr, col, dinv, (const uint2*)sxw1h,
                                                               xw0, b1, (uint2*)h16, (uint2*)sh16);
    gather2_out      <<<(N_NODES + 63) / 64, 256, 0, stream>>>(rowptr, col, dinv, (const uint2*)sh16,
                                                               (const uint2*)h16, W2, b2, out);
}